// Round 2
// baseline (372.090 us; speedup 1.0000x reference)
//
#include <hip/hip_runtime.h>
#include <hip/hip_bf16.h>

#define GROUPS 16
#define BSZ    8192
#define CHN    256

using f32x4  = __attribute__((ext_vector_type(4))) float;
using bf16x8 = __attribute__((ext_vector_type(8))) __bf16;

static __device__ __forceinline__ unsigned short f32_bf16(float f) {
    unsigned int u = __builtin_bit_cast(unsigned int, f);
    u = (u + 0x7FFFu + ((u >> 16) & 1u)) >> 16;   // RNE (NaN not a concern here)
    return (unsigned short)u;
}
static __device__ __forceinline__ unsigned int pack_bf16x2(float lo, float hi) {
    return (unsigned int)f32_bf16(lo) | ((unsigned int)f32_bf16(hi) << 16);
}

// ---------------------------------------------------------------------------
// Kernel B: compose M = H_0 H_1 ... H_255 per group, row-parallel.
// (unchanged this round — next round's top-5 will reveal its true cost)
// ---------------------------------------------------------------------------
__global__ __launch_bounds__(256) void compose_m(const float* __restrict__ weight,
                                                 unsigned short* __restrict__ Mt) {
    __shared__ float wbuf[16 * 260];   // 16 staged columns, stride 260 (pad)
    __shared__ float coefbuf[16];

    const int t    = threadIdx.x;
    const int g    = blockIdx.x >> 4;
    const int r0   = (blockIdx.x & 15) * 16;
    const int lane = t & 15;           // lane within row-group
    const int rg   = (t >> 4) & 3;     // row within wave
    const int wave = t >> 6;
    const int r    = r0 + wave * 4 + rg;   // this task's M row (0..255)

    // m held in registers: c = 4*lane + 64*j + e  (j=0..3, e=0..3)
    float4 m4[4];
#pragma unroll
    for (int j = 0; j < 4; ++j) {
        const int cb = 4 * lane + 64 * j;
        m4[j].x = (cb + 0 == r) ? 1.0f : 0.0f;
        m4[j].y = (cb + 1 == r) ? 1.0f : 0.0f;
        m4[j].z = (cb + 2 == r) ? 1.0f : 0.0f;
        m4[j].w = (cb + 3 == r) ? 1.0f : 0.0f;
    }

    const float* wg = weight + (size_t)g * CHN * CHN;
    const int e16 = t & 15;    // which column (i-offset) this thread stages
    const int nb  = t >> 4;    // n base (stride 16)

    for (int iw = 0; iw < 16; ++iw) {
        const int i0 = iw * 16;
        // issue global loads for this window before the barrier (no LDS hazard)
        float ld[16];
#pragma unroll
        for (int k = 0; k < 16; ++k)
            ld[k] = wg[(nb + 16 * k) * CHN + i0 + e16];
        __syncthreads();   // previous window fully consumed
#pragma unroll
        for (int k = 0; k < 16; ++k)
            wbuf[e16 * 260 + nb + 16 * k] = ld[k];
        __syncthreads();
        // coefs: thread group e (=t>>4) computes 2/(w_e . w_e)
        {
            const int e = t >> 4;
            float s = 0.0f;
#pragma unroll
            for (int k = 0; k < 16; ++k) {
                const float w = wbuf[e * 260 + lane + 16 * k];
                s += w * w;
            }
            s += __shfl_xor(s, 1);
            s += __shfl_xor(s, 2);
            s += __shfl_xor(s, 4);
            s += __shfl_xor(s, 8);
            if (lane == 0) coefbuf[e] = 2.0f / s;
        }
        __syncthreads();
        // 16 sequential reflection steps
#pragma unroll
        for (int e = 0; e < 16; ++e) {
            float4 w4[4];
#pragma unroll
            for (int j = 0; j < 4; ++j)
                w4[j] = *(const float4*)&wbuf[e * 260 + 4 * lane + 64 * j];
            float p = 0.0f;
#pragma unroll
            for (int j = 0; j < 4; ++j)
                p += m4[j].x * w4[j].x + m4[j].y * w4[j].y +
                     m4[j].z * w4[j].z + m4[j].w * w4[j].w;
            p += __shfl_xor(p, 1);
            p += __shfl_xor(p, 2);
            p += __shfl_xor(p, 4);
            p += __shfl_xor(p, 8);
            const float s = coefbuf[e] * p;
#pragma unroll
            for (int j = 0; j < 4; ++j) {
                m4[j].x -= s * w4[j].x;
                m4[j].y -= s * w4[j].y;
                m4[j].z -= s * w4[j].z;
                m4[j].w -= s * w4[j].w;
            }
        }
    }

    // write Mt[g][c][r] (bf16) — scattered u16 stores, tiny total (2 MB)
    unsigned short* mg = Mt + (size_t)g * CHN * CHN;
#pragma unroll
    for (int j = 0; j < 4; ++j) {
        const int cb = 4 * lane + 64 * j;
        mg[(size_t)(cb + 0) * CHN + r] = f32_bf16(m4[j].x);
        mg[(size_t)(cb + 1) * CHN + r] = f32_bf16(m4[j].y);
        mg[(size_t)(cb + 2) * CHN + r] = f32_bf16(m4[j].z);
        mg[(size_t)(cb + 3) * CHN + r] = f32_bf16(m4[j].w);
    }
}

// ---------------------------------------------------------------------------
// Kernel C: out[g] = x[g] (8192x256 f32->bf16) @ M[g] (256x256 bf16), f32 acc.
// LDS-FREE / BARRIER-FREE rewrite.
//   Block: 512 thr = 8 waves as 2x4; block tile 128 rows x 256 cols;
//   wave tile 64x64 (4x4 MFMA 16x16x32 tiles), K streamed in 8 steps of 32.
// A-fragments: loaded per-wave straight from global x (f32, 2x dwordx4/lane),
//   converted in-register (identical RNE as before). 4 col-waves re-read the
//   same rows within a few hundred cycles -> served by L2.
// B-fragments: loaded straight from global Mt (bf16, 16B/lane); Mt is 128 KB/
//   group and L2-resident across all 64 blocks of the group.
// No __syncthreads anywhere -> no vmcnt(0) barrier drain; every wave streams
//   with ~12 outstanding 1KB loads. 12 waves/CU >> Little's-law requirement.
// Numerically bit-identical to the previous LDS version (same conversion,
//   same MFMA order).
// ---------------------------------------------------------------------------
__global__ __launch_bounds__(512, 3) void gemm_xm(const float* __restrict__ x,
                                                  const unsigned short* __restrict__ Mt,
                                                  float* __restrict__ out) {
    const int t    = threadIdx.x;
    const int g    = blockIdx.x >> 6;
    const int rb   = blockIdx.x & 63;
    const int r0   = rb * 128;
    const int l    = t & 63;
    const int wave = t >> 6;     // 0..7
    const int wr   = wave >> 2;  // 0..1  (row half)
    const int wc   = wave & 3;   // 0..3  (col quarter)
    const int lm   = l & 15;
    const int q    = l >> 4;     // 0..3

    // lane-resolved base pointers (rows / cols owned by this lane)
    const float*          xg = x  + ((size_t)g * BSZ + r0 + wr * 64 + lm) * CHN;
    const unsigned short* mg = Mt + ((size_t)g * CHN + wc * 64 + lm) * CHN;

    f32x4 acc[4][4];
#pragma unroll
    for (int mi = 0; mi < 4; ++mi)
#pragma unroll
        for (int ni = 0; ni < 4; ++ni)
            acc[mi][ni] = (f32x4){0.f, 0.f, 0.f, 0.f};

#pragma unroll 1
    for (int ks = 0; ks < 8; ++ks) {
        const int ko = 32 * ks + 8 * q;   // k offset for this lane's fragment

        // ---- issue all 12 global loads back-to-back (A first, then B) ----
        float4 ax[4][2];
#pragma unroll
        for (int mi = 0; mi < 4; ++mi) {
            const float* p = xg + (size_t)(mi * 16) * CHN + ko;
            ax[mi][0] = *(const float4*)(p);
            ax[mi][1] = *(const float4*)(p + 4);
        }
        uint4 bu[4];
#pragma unroll
        for (int ni = 0; ni < 4; ++ni)
            bu[ni] = *(const uint4*)(mg + (size_t)(ni * 16) * CHN + ko);

        // ---- convert A to bf16 (same RNE as the old LDS-staging path) ----
        bf16x8 a[4], b[4];
#pragma unroll
        for (int mi = 0; mi < 4; ++mi) {
            uint4 u;
            u.x = pack_bf16x2(ax[mi][0].x, ax[mi][0].y);
            u.y = pack_bf16x2(ax[mi][0].z, ax[mi][0].w);
            u.z = pack_bf16x2(ax[mi][1].x, ax[mi][1].y);
            u.w = pack_bf16x2(ax[mi][1].z, ax[mi][1].w);
            a[mi] = __builtin_bit_cast(bf16x8, u);
        }
#pragma unroll
        for (int ni = 0; ni < 4; ++ni)
            b[ni] = __builtin_bit_cast(bf16x8, bu[ni]);

        // ---- 16 MFMAs ----
#pragma unroll
        for (int mi = 0; mi < 4; ++mi)
#pragma unroll
            for (int ni = 0; ni < 4; ++ni)
                acc[mi][ni] = __builtin_amdgcn_mfma_f32_16x16x32_bf16(
                    a[mi], b[ni], acc[mi][ni], 0, 0, 0);
    }

    // epilogue: D layout col = lane&15, row = (lane>>4)*4 + reg
    float* og = out + ((size_t)g * BSZ + r0) * CHN;
#pragma unroll
    for (int mi = 0; mi < 4; ++mi) {
#pragma unroll
        for (int ni = 0; ni < 4; ++ni) {
            const int col = wc * 64 + ni * 16 + lm;
#pragma unroll
            for (int reg = 0; reg < 4; ++reg) {
                const int row = wr * 64 + mi * 16 + q * 4 + reg;
                og[(size_t)row * CHN + col] = acc[mi][ni][reg];
            }
        }
    }
}

extern "C" void kernel_launch(void* const* d_in, const int* in_sizes, int n_in,
                              void* d_out, int out_size, void* d_ws, size_t ws_size,
                              hipStream_t stream) {
    const float* x = (const float*)d_in[0];
    const float* w = (const float*)d_in[1];
    float* out = (float*)d_out;
    unsigned short* Mt = (unsigned short*)d_ws;   // 16*256*256 bf16 = 2 MB

    hipLaunchKernelGGL(compose_m, dim3(GROUPS * 16), dim3(256), 0, stream, w, Mt);
    hipLaunchKernelGGL(gemm_xm,   dim3(GROUPS * 64), dim3(512), 0, stream, x, Mt, out);
}

// Round 3
// 315.961 us; speedup vs baseline: 1.1776x; 1.1776x over previous
//
#include <hip/hip_runtime.h>
#include <hip/hip_bf16.h>

#define GROUPS 16
#define BSZ    8192
#define CHN    256

using f32x4  = __attribute__((ext_vector_type(4))) float;
using bf16x8 = __attribute__((ext_vector_type(8))) __bf16;

static __device__ __forceinline__ unsigned short f32_bf16(float f) {
    unsigned int u = __builtin_bit_cast(unsigned int, f);
    u = (u + 0x7FFFu + ((u >> 16) & 1u)) >> 16;   // RNE (NaN not a concern here)
    return (unsigned short)u;
}
static __device__ __forceinline__ unsigned int pack_bf16x2(float lo, float hi) {
    return (unsigned int)f32_bf16(lo) | ((unsigned int)f32_bf16(hi) << 16);
}

// async global -> LDS, 16 B per lane. Dest is wave-uniform base + lane*16.
static __device__ __forceinline__ void gload_lds16(const void* g, void* l) {
    __builtin_amdgcn_global_load_lds(
        (const __attribute__((address_space(1))) unsigned int*)g,
        (__attribute__((address_space(3))) unsigned int*)l, 16, 0, 0);
}

// ---------------------------------------------------------------------------
// Kernel B: compose M = H_0 H_1 ... H_255 per group, row-parallel. (unchanged)
// ---------------------------------------------------------------------------
__global__ __launch_bounds__(256) void compose_m(const float* __restrict__ weight,
                                                 unsigned short* __restrict__ Mt) {
    __shared__ float wbuf[16 * 260];   // 16 staged columns, stride 260 (pad)
    __shared__ float coefbuf[16];

    const int t    = threadIdx.x;
    const int g    = blockIdx.x >> 4;
    const int r0   = (blockIdx.x & 15) * 16;
    const int lane = t & 15;
    const int rg   = (t >> 4) & 3;
    const int wave = t >> 6;
    const int r    = r0 + wave * 4 + rg;

    float4 m4[4];
#pragma unroll
    for (int j = 0; j < 4; ++j) {
        const int cb = 4 * lane + 64 * j;
        m4[j].x = (cb + 0 == r) ? 1.0f : 0.0f;
        m4[j].y = (cb + 1 == r) ? 1.0f : 0.0f;
        m4[j].z = (cb + 2 == r) ? 1.0f : 0.0f;
        m4[j].w = (cb + 3 == r) ? 1.0f : 0.0f;
    }

    const float* wg = weight + (size_t)g * CHN * CHN;
    const int e16 = t & 15;
    const int nb  = t >> 4;

    for (int iw = 0; iw < 16; ++iw) {
        const int i0 = iw * 16;
        float ld[16];
#pragma unroll
        for (int k = 0; k < 16; ++k)
            ld[k] = wg[(nb + 16 * k) * CHN + i0 + e16];
        __syncthreads();
#pragma unroll
        for (int k = 0; k < 16; ++k)
            wbuf[e16 * 260 + nb + 16 * k] = ld[k];
        __syncthreads();
        {
            const int e = t >> 4;
            float s = 0.0f;
#pragma unroll
            for (int k = 0; k < 16; ++k) {
                const float w = wbuf[e * 260 + lane + 16 * k];
                s += w * w;
            }
            s += __shfl_xor(s, 1);
            s += __shfl_xor(s, 2);
            s += __shfl_xor(s, 4);
            s += __shfl_xor(s, 8);
            if (lane == 0) coefbuf[e] = 2.0f / s;
        }
        __syncthreads();
#pragma unroll
        for (int e = 0; e < 16; ++e) {
            float4 w4[4];
#pragma unroll
            for (int j = 0; j < 4; ++j)
                w4[j] = *(const float4*)&wbuf[e * 260 + 4 * lane + 64 * j];
            float p = 0.0f;
#pragma unroll
            for (int j = 0; j < 4; ++j)
                p += m4[j].x * w4[j].x + m4[j].y * w4[j].y +
                     m4[j].z * w4[j].z + m4[j].w * w4[j].w;
            p += __shfl_xor(p, 1);
            p += __shfl_xor(p, 2);
            p += __shfl_xor(p, 4);
            p += __shfl_xor(p, 8);
            const float s = coefbuf[e] * p;
#pragma unroll
            for (int j = 0; j < 4; ++j) {
                m4[j].x -= s * w4[j].x;
                m4[j].y -= s * w4[j].y;
                m4[j].z -= s * w4[j].z;
                m4[j].w -= s * w4[j].w;
            }
        }
    }

    unsigned short* mg = Mt + (size_t)g * CHN * CHN;
#pragma unroll
    for (int j = 0; j < 4; ++j) {
        const int cb = 4 * lane + 64 * j;
        mg[(size_t)(cb + 0) * CHN + r] = f32_bf16(m4[j].x);
        mg[(size_t)(cb + 1) * CHN + r] = f32_bf16(m4[j].y);
        mg[(size_t)(cb + 2) * CHN + r] = f32_bf16(m4[j].z);
        mg[(size_t)(cb + 3) * CHN + r] = f32_bf16(m4[j].w);
    }
}

// ---------------------------------------------------------------------------
// Kernel C: out[g] = x[g] (8192x256 f32->bf16) @ M[g] (256x256 bf16), f32 acc.
// Double-buffered, 1 barrier per K-chunk(=32), one-chunk-ahead prefetch.
//   A: reg-staged (coalesced 128B row slices), packed bf16, LDS stride 20 dw
//      (16B-aligned b128 frags; 5 odd -> uniform banks, no extra conflicts).
//   B: global_load_lds direct copy (linear [col][16dw], identity mapping;
//      <=2 lanes/bank per dword phase = free).
// Prefetch for chunk kc+1 issued right AFTER __syncthreads(kc): all waves past
// that barrier => compute kc-1 done => the destination buffer is free. Loads
// fly across the whole compute phase; the barrier's vmcnt(0) only drains loads
// needed immediately after it. FP order identical to the 330us baseline.
// ---------------------------------------------------------------------------
#define ABUF 2560          // A buffer: 128 rows * 20 dwords
#define BUFSZ 6656         // A (2560) + B (256*16 = 4096) dwords per buffer

__global__ __launch_bounds__(512, 4) void gemm_xm(const float* __restrict__ x,
                                                  const unsigned short* __restrict__ Mt,
                                                  float* __restrict__ out) {
    __shared__ __align__(16) unsigned int lds[2 * BUFSZ];   // 53248 B

    const int t    = threadIdx.x;
    const int g    = blockIdx.x >> 6;
    const int rb   = blockIdx.x & 63;
    const int r0   = rb * 128;
    const int l    = t & 63;
    const int wave = t >> 6;     // 0..7
    const int wr   = wave >> 2;  // 0..1
    const int wc   = wave & 3;   // 0..3
    const int lm   = l & 15;
    const int q    = l >> 4;     // 0..3

    const float*          xg = x  + ((size_t)g * BSZ + r0) * CHN;
    const unsigned short* mg = Mt +  (size_t)g * CHN * CHN;

    // staging maps
    const int ar = t >> 3;           // A row (0..63), +64 for second load
    const int as = t & 7;            // A seg: float4 index within 32-k slice
    const int bc = (wave << 4) + ((l >> 2) & 15);   // B col for lane (it0)
    const int bq = l & 3;            // B 16B slot within col

    f32x4 acc[4][4];
#pragma unroll
    for (int mi = 0; mi < 4; ++mi)
#pragma unroll
        for (int ni = 0; ni < 4; ++ni)
            acc[mi][ni] = (f32x4){0.f, 0.f, 0.f, 0.f};

    float4 sA[2][2];   // [set][half] — static-indexed via full unroll

    // ---- prologue: chunk 0 ----
    sA[0][0] = *(const float4*)&xg[(size_t)ar * CHN + 4 * as];
    sA[0][1] = *(const float4*)&xg[(size_t)(ar + 64) * CHN + 4 * as];
    {
        unsigned int* bb = lds + ABUF;
        gload_lds16(mg + (size_t)bc * CHN + 8 * bq,          &bb[wave * 256]);
        gload_lds16(mg + (size_t)(bc + 128) * CHN + 8 * bq,  &bb[(wave + 8) * 256]);
    }

#pragma unroll
    for (int kc = 0; kc < 8; ++kc) {
        const int cur = kc & 1;
        unsigned int* ab = lds + cur * BUFSZ;
        unsigned int* bb = ab + ABUF;

        // pack + write A chunk kc (waits this chunk's A loads via counted vmcnt)
        {
            uint2 p0, p1;
            p0.x = pack_bf16x2(sA[cur][0].x, sA[cur][0].y);
            p0.y = pack_bf16x2(sA[cur][0].z, sA[cur][0].w);
            p1.x = pack_bf16x2(sA[cur][1].x, sA[cur][1].y);
            p1.y = pack_bf16x2(sA[cur][1].z, sA[cur][1].w);
            *(uint2*)&ab[ar * 20 + 2 * as]        = p0;
            *(uint2*)&ab[(ar + 64) * 20 + 2 * as] = p1;
        }
        __syncthreads();   // buf[cur] ready; all waves finished compute kc-1

        // prefetch chunk kc+1 into the other buffer / reg set
        if (kc < 7) {
            const int nxt = cur ^ 1;
            const int k0  = (kc + 1) * 32;
            sA[nxt][0] = *(const float4*)&xg[(size_t)ar * CHN + k0 + 4 * as];
            sA[nxt][1] = *(const float4*)&xg[(size_t)(ar + 64) * CHN + k0 + 4 * as];
            unsigned int* bbn = lds + nxt * BUFSZ + ABUF;
            gload_lds16(mg + (size_t)bc * CHN + k0 + 8 * bq,         &bbn[wave * 256]);
            gload_lds16(mg + (size_t)(bc + 128) * CHN + k0 + 8 * bq, &bbn[(wave + 8) * 256]);
        }

        // compute chunk kc
        bf16x8 a[4];
#pragma unroll
        for (int mi = 0; mi < 4; ++mi) {
            const int rr = wr * 64 + mi * 16 + lm;
            a[mi] = __builtin_bit_cast(bf16x8, *(const uint4*)&ab[rr * 20 + 4 * q]);
        }
#pragma unroll
        for (int ni = 0; ni < 4; ++ni) {
            const int cc = wc * 64 + ni * 16 + lm;
            const bf16x8 b = __builtin_bit_cast(bf16x8, *(const uint4*)&bb[cc * 16 + 4 * q]);
#pragma unroll
            for (int mi = 0; mi < 4; ++mi)
                acc[mi][ni] = __builtin_amdgcn_mfma_f32_16x16x32_bf16(
                    a[mi], b, acc[mi][ni], 0, 0, 0);
        }
    }

    // epilogue: D layout col = lane&15, row = (lane>>4)*4 + reg
    float* og = out + ((size_t)g * BSZ + r0) * CHN;
#pragma unroll
    for (int mi = 0; mi < 4; ++mi) {
#pragma unroll
        for (int ni = 0; ni < 4; ++ni) {
            const int col = wc * 64 + ni * 16 + lm;
#pragma unroll
            for (int reg = 0; reg < 4; ++reg) {
                const int row = wr * 64 + mi * 16 + q * 4 + reg;
                og[(size_t)row * CHN + col] = acc[mi][ni][reg];
            }
        }
    }
}

extern "C" void kernel_launch(void* const* d_in, const int* in_sizes, int n_in,
                              void* d_out, int out_size, void* d_ws, size_t ws_size,
                              hipStream_t stream) {
    const float* x = (const float*)d_in[0];
    const float* w = (const float*)d_in[1];
    float* out = (float*)d_out;
    unsigned short* Mt = (unsigned short*)d_ws;   // 16*256*256 bf16 = 2 MB

    hipLaunchKernelGGL(compose_m, dim3(GROUPS * 16), dim3(256), 0, stream, w, Mt);
    hipLaunchKernelGGL(gemm_xm,   dim3(GROUPS * 64), dim3(512), 0, stream, x, Mt, out);
}